// Round 3
// baseline (136.750 us; speedup 1.0000x reference)
//
#include <hip/hip_runtime.h>
#include <stdint.h>

// Problem constants (from reference setup_inputs)
#define BATCH 4096
#define ISZ   512
#define OSZ   512
#define KDIM  (ISZ * 8)      // 4096, contraction dim: k = i*8 + d

// GEMM tiling
#define TM 128
#define TN 256
#define BK 64
#define SPLITK 8

typedef __bf16 bf16x8 __attribute__((ext_vector_type(8)));
typedef float  f32x4  __attribute__((ext_vector_type(4)));

__device__ __forceinline__ unsigned short f2bf(float f) {
    // round-to-nearest-even fp32 -> bf16 (no NaN inputs here)
    uint32_t u = __float_as_uint(f);
    u = (u + 0x7FFFu + ((u >> 16) & 1u)) >> 16;
    return (unsigned short)u;
}

// jac[b][i*8+d] = P_d(tanh(x[b][i])), alpha=beta=1 Jacobi recurrence.
__global__ __launch_bounds__(256) void jacobi_precompute(
    const float* __restrict__ x, unsigned short* __restrict__ jac, int n)
{
    int idx = blockIdx.x * 256 + threadIdx.x;
    if (idx >= n) return;
    float t  = tanhf(x[idx]);
    float p0 = 1.0f;
    float p1 = 2.0f * t;                       // 0.5*(a+b+2)*x - 0.5*(a-b)
    float p2 = (1.875f     * t) * p1 - 0.75f       * p0;
    float p3 = (1.8666667f * t) * p2 - 0.8f        * p1;
    float p4 = (1.875f     * t) * p3 - 0.83333333f * p2;
    float p5 = (1.8857143f * t) * p4 - 0.85714287f * p3;
    float p6 = (1.8958333f * t) * p5 - 0.875f      * p4;
    float p7 = (1.9047619f * t) * p6 - 0.88888889f * p5;
    uint4 o;
    o.x = (uint32_t)f2bf(p0) | ((uint32_t)f2bf(p1) << 16);
    o.y = (uint32_t)f2bf(p2) | ((uint32_t)f2bf(p3) << 16);
    o.z = (uint32_t)f2bf(p4) | ((uint32_t)f2bf(p5) << 16);
    o.w = (uint32_t)f2bf(p6) | ((uint32_t)f2bf(p7) << 16);
    *reinterpret_cast<uint4*>(jac + (size_t)idx * 8) = o;   // 16B aligned
}

// flat fp32 -> bf16 convert (coef already k-contiguous: [O][I][D] -> [O][K])
__global__ __launch_bounds__(256) void convert_bf16(
    const float* __restrict__ src, unsigned short* __restrict__ dst, int n4)
{
    int idx = blockIdx.x * 256 + threadIdx.x;
    if (idx >= n4) return;
    float4 v = reinterpret_cast<const float4*>(src)[idx];
    uint2 o;
    o.x = (uint32_t)f2bf(v.x) | ((uint32_t)f2bf(v.y) << 16);
    o.y = (uint32_t)f2bf(v.z) | ((uint32_t)f2bf(v.w) << 16);
    reinterpret_cast<uint2*>(dst)[idx] = o;
}

// C[M][N] += A[M][Ks] * Bm[N][Ks]^T over split-K partitions (atomicAdd).
// 128x256 block tile, BK=64, 512 threads = 8 waves (2x4), wave tile 64x64
// via 4x4 of mfma_f32_16x16x32_bf16 (layout verified rounds 1-2).
// LDS tiles stored as 16B chunks with XOR swizzle: chunk (row, c) at slot
// row*8 + (c ^ (row&7)) -> bank-balanced fragment reads (round 2 measured
// SQ_LDS_BANK_CONFLICT == 0) while keeping global_load_lds's wave-uniform
// base + lane*16 destination contract (swizzle applied to the per-lane
// *source* address; permutation stays within a 128B line so coalescing holds).
__global__ __launch_bounds__(512, 4) void gemm_splitk(
    const unsigned short* __restrict__ A,   // [M][K] bf16 bits
    const unsigned short* __restrict__ Bm,  // [N][K] bf16 bits
    float* __restrict__ C, int M, int N, int K)
{
    __shared__ __align__(16) unsigned short As[TM * BK];   // 16 KB
    __shared__ __align__(16) unsigned short Bs[TN * BK];   // 32 KB

    const int tid  = threadIdx.x;
    const int wave = tid >> 6;
    const int lane = tid & 63;
    const int wm   = (wave >> 2) * 64;      // wave row offset in tile (0,64)
    const int wn   = (wave & 3) * 64;       // wave col offset (0,64,128,192)

    const size_t baseA = (size_t)blockIdx.x * TM * K;
    const size_t baseB = (size_t)blockIdx.y * TN * K;
    const int kper = K / SPLITK;            // 512
    const int kbeg = blockIdx.z * kper;
    const int kend = kbeg + kper;

    f32x4 acc[4][4] = {};

    const int mrow = lane & 15;             // m within 16x16 tile
    const int kc   = lane >> 4;             // 16B-chunk column offset within k

    for (int k0 = kbeg; k0 < kend; k0 += BK) {
        // A tile: 128x64 bf16 = 16 KB = 1024 chunks; 512 threads x 2 its.
        #pragma unroll
        for (int it = 0; it < 2; ++it) {
            int s    = it * 512 + tid;
            int row  = s >> 3;
            int csrc = (s & 7) ^ (row & 7);
            const unsigned short* gA = A + baseA + (size_t)row * K + k0 + csrc * 8;
            unsigned short* lA = As + (size_t)(it * 512 + wave * 64) * 8; // uniform
            __builtin_amdgcn_global_load_lds(
                (const __attribute__((address_space(1))) uint32_t*)gA,
                (__attribute__((address_space(3))) uint32_t*)lA, 16, 0, 0);
        }
        // B tile: 256x64 bf16 = 32 KB = 2048 chunks; 512 threads x 4 its.
        #pragma unroll
        for (int it = 0; it < 4; ++it) {
            int s    = it * 512 + tid;
            int row  = s >> 3;
            int csrc = (s & 7) ^ (row & 7);
            const unsigned short* gB = Bm + baseB + (size_t)row * K + k0 + csrc * 8;
            unsigned short* lB = Bs + (size_t)(it * 512 + wave * 64) * 8;
            __builtin_amdgcn_global_load_lds(
                (const __attribute__((address_space(1))) uint32_t*)gB,
                (__attribute__((address_space(3))) uint32_t*)lB, 16, 0, 0);
        }
        __syncthreads();   // drains vmcnt for global_load_lds

        #pragma unroll
        for (int ks = 0; ks < BK; ks += 32) {
            bf16x8 aF[4], bF[4];
            const int cbase = (ks >> 3) + kc;   // 16B chunk col in [0,8)
            #pragma unroll
            for (int mi = 0; mi < 4; ++mi) {
                int r = wm + mi * 16 + mrow;
                int slot = r * 8 + (cbase ^ (r & 7));
                aF[mi] = *reinterpret_cast<const bf16x8*>(As + (size_t)slot * 8);
            }
            #pragma unroll
            for (int ni = 0; ni < 4; ++ni) {
                int r = wn + ni * 16 + mrow;
                int slot = r * 8 + (cbase ^ (r & 7));
                bF[ni] = *reinterpret_cast<const bf16x8*>(Bs + (size_t)slot * 8);
            }
            #pragma unroll
            for (int mi = 0; mi < 4; ++mi)
                #pragma unroll
                for (int ni = 0; ni < 4; ++ni)
                    acc[mi][ni] = __builtin_amdgcn_mfma_f32_16x16x32_bf16(
                        aF[mi], bF[ni], acc[mi][ni], 0, 0, 0);
        }
        __syncthreads();
    }

    // C/D layout (m89-verified): col = lane&15, row = (lane>>4)*4 + r
    const int orow = blockIdx.x * TM + wm + (lane >> 4) * 4;
    const int ocol = blockIdx.y * TN + wn + (lane & 15);
    #pragma unroll
    for (int mi = 0; mi < 4; ++mi)
        #pragma unroll
        for (int ni = 0; ni < 4; ++ni)
            #pragma unroll
            for (int r = 0; r < 4; ++r)
                unsafeAtomicAdd(
                    &C[(size_t)(orow + mi * 16 + r) * N + ocol + ni * 16],
                    acc[mi][ni][r]);
}

extern "C" void kernel_launch(void* const* d_in, const int* in_sizes, int n_in,
                              void* d_out, int out_size, void* d_ws, size_t ws_size,
                              hipStream_t stream)
{
    const float* x    = (const float*)d_in[0];   // [4096][512]
    const float* coef = (const float*)d_in[1];   // [512][512][8]
    float* out = (float*)d_out;                  // [4096][512]

    // workspace: jac bf16 [4096][4096] (32 MB) + coef bf16 [512][4096] (4 MB)
    unsigned short* jac   = (unsigned short*)d_ws;
    unsigned short* coefb = jac + (size_t)BATCH * KDIM;

    // split-K accumulates into d_out with atomics -> zero it first
    hipMemsetAsync(out, 0, (size_t)BATCH * OSZ * sizeof(float), stream);

    int nx = BATCH * ISZ;                        // 2,097,152
    jacobi_precompute<<<(nx + 255) / 256, 256, 0, stream>>>(x, jac, nx);

    int n4 = (OSZ * KDIM) / 4;                   // 524,288
    convert_bf16<<<(n4 + 255) / 256, 256, 0, stream>>>(coef, coefb, n4);

    dim3 grid(BATCH / TM, OSZ / TN, SPLITK);     // 32 x 2 x 8 = 512 blocks
    gemm_splitk<<<grid, 512, 0, stream>>>(jac, coefb, out, BATCH, OSZ, KDIM);
}

// Round 4
// 102.414 us; speedup vs baseline: 1.3353x; 1.3353x over previous
//
#include <hip/hip_runtime.h>
#include <stdint.h>

// Problem constants (from reference setup_inputs)
#define BATCH 4096
#define ISZ   512
#define OSZ   512
#define KDIM  4096           // contraction dim: k = i*8 + d

// GEMM tiling
#define TM 128
#define TN 128
#define BK 64
#define SPLITK 4

typedef __bf16 bf16x8 __attribute__((ext_vector_type(8)));
typedef float  f32x4  __attribute__((ext_vector_type(4)));

__device__ __forceinline__ unsigned short f2bf(float f) {
    // round-to-nearest-even fp32 -> bf16 (no NaN inputs here)
    uint32_t u = __float_as_uint(f);
    u = (u + 0x7FFFu + ((u >> 16) & 1u)) >> 16;
    return (unsigned short)u;
}

// flat fp32 -> bf16 convert (coef already k-contiguous: [O][I][D] -> [O][K])
__global__ __launch_bounds__(256) void convert_bf16(
    const float* __restrict__ src, unsigned short* __restrict__ dst, int n4)
{
    int idx = blockIdx.x * 256 + threadIdx.x;
    if (idx >= n4) return;
    float4 v = reinterpret_cast<const float4*>(src)[idx];
    uint2 o;
    o.x = (uint32_t)f2bf(v.x) | ((uint32_t)f2bf(v.y) << 16);
    o.y = (uint32_t)f2bf(v.z) | ((uint32_t)f2bf(v.w) << 16);
    reinterpret_cast<uint2*>(dst)[idx] = o;
}

// Fused Jacobi + GEMM, split-K partials (NO atomics - R3 showed the atomic
// epilogue costs ~50 us of TCC serialization).
// Cp[z][M][N] = A[M][Kz] * Bm[N][Kz]^T where A[m][i*8+d] = P_d(tanh(x[m][i]))
// is computed IN-KERNEL per k-tile (a 128x64 A-tile needs only 128x8 x-floats).
// 128x128 block tile, BK=64, 256 threads = 4 waves (2x2), wave tile 64x64 via
// 4x4 of mfma_f32_16x16x32_bf16 (layout verified rounds 1-3).
// LDS tiles: 16B chunks, XOR swizzle slot = row*8 + (c ^ (row&7)) -> measured
// SQ_LDS_BANK_CONFLICT == 0 in rounds 2-3. B path keeps the global_load_lds
// wave-uniform-base + lane*16 contract (swizzle on per-lane *source* address);
// A path is plain ds_write_b128 (per-lane scatter allowed), same slot map.
__global__ __launch_bounds__(256) void gemm_fused(
    const float* __restrict__ X,            // [BATCH][ISZ] fp32
    const unsigned short* __restrict__ Bm,  // [OSZ][KDIM] bf16 bits
    float* __restrict__ Cp, int M, int N, int K)
{
    __shared__ __align__(16) unsigned short As[TM * BK];   // 16 KB
    __shared__ __align__(16) unsigned short Bs[TN * BK];   // 16 KB

    const int tid  = threadIdx.x;
    const int wave = tid >> 6;
    const int lane = tid & 63;
    const int wm   = (wave >> 1) * 64;      // wave row offset in tile
    const int wn   = (wave & 1) * 64;       // wave col offset in tile

    const int    m0    = blockIdx.x * TM;
    const size_t baseB = (size_t)blockIdx.y * TN * K;
    const int kper = K / SPLITK;            // 1024
    const int kbeg = blockIdx.z * kper;
    const int kend = kbeg + kper;

    f32x4 acc[4][4] = {};

    const int mrow = lane & 15;             // m within 16x16 tile
    const int kc   = lane >> 4;             // 16B-chunk column offset within k

    // A-compute assignment: thread t -> row xr = t>>1, chunk cols xc..xc+3
    const int xr = tid >> 1;
    const int xc = (tid & 1) * 4;

    for (int k0 = kbeg; k0 < kend; k0 += BK) {
        // ---- issue B staging first (loads fly while we compute A) ----
        // B tile: 128x64 bf16 = 16 KB = 1024 chunks; 256 threads x 4 its.
        #pragma unroll
        for (int it = 0; it < 4; ++it) {
            int s    = it * 256 + tid;
            int row  = s >> 3;
            int csrc = (s & 7) ^ (row & 7);
            const unsigned short* gB = Bm + baseB + (size_t)row * K + k0 + csrc * 8;
            unsigned short* lB = Bs + (size_t)(it * 256 + wave * 64) * 8; // uniform
            __builtin_amdgcn_global_load_lds(
                (const __attribute__((address_space(1))) uint32_t*)gB,
                (__attribute__((address_space(3))) uint32_t*)lB, 16, 0, 0);
        }

        // ---- compute A tile from x: chunk (r, c) = jacobi8(tanh(x[m0+r][i0+c]))
        const int i0 = k0 >> 3;
        float4 xv = *reinterpret_cast<const float4*>(
            X + (size_t)(m0 + xr) * ISZ + i0 + xc);
        const float xs[4] = {xv.x, xv.y, xv.z, xv.w};
        #pragma unroll
        for (int j = 0; j < 4; ++j) {
            // tanh(x) = 1 - 2/(exp(2x)+1); v_exp+v_rcp err ~1e-6 << bf16 ulp
            float e  = __expf(2.0f * xs[j]);
            float t  = 1.0f - 2.0f * __builtin_amdgcn_rcpf(e + 1.0f);
            float p0 = 1.0f;
            float p1 = 2.0f * t;
            float p2 = (1.875f     * t) * p1 - 0.75f       * p0;
            float p3 = (1.8666667f * t) * p2 - 0.8f        * p1;
            float p4 = (1.875f     * t) * p3 - 0.83333333f * p2;
            float p5 = (1.8857143f * t) * p4 - 0.85714287f * p3;
            float p6 = (1.8958333f * t) * p5 - 0.875f      * p4;
            float p7 = (1.9047619f * t) * p6 - 0.88888889f * p5;
            uint4 o;
            o.x = (uint32_t)f2bf(p0) | ((uint32_t)f2bf(p1) << 16);
            o.y = (uint32_t)f2bf(p2) | ((uint32_t)f2bf(p3) << 16);
            o.z = (uint32_t)f2bf(p4) | ((uint32_t)f2bf(p5) << 16);
            o.w = (uint32_t)f2bf(p6) | ((uint32_t)f2bf(p7) << 16);
            int slot = xr * 8 + ((xc + j) ^ (xr & 7));
            *reinterpret_cast<uint4*>(As + (size_t)slot * 8) = o;
        }
        __syncthreads();   // drains vmcnt (B) + lgkmcnt (A writes)

        #pragma unroll
        for (int ks = 0; ks < BK; ks += 32) {
            bf16x8 aF[4], bF[4];
            const int cbase = (ks >> 3) + kc;   // 16B chunk col in [0,8)
            #pragma unroll
            for (int mi = 0; mi < 4; ++mi) {
                int r = wm + mi * 16 + mrow;
                int slot = r * 8 + (cbase ^ (r & 7));
                aF[mi] = *reinterpret_cast<const bf16x8*>(As + (size_t)slot * 8);
            }
            #pragma unroll
            for (int ni = 0; ni < 4; ++ni) {
                int r = wn + ni * 16 + mrow;
                int slot = r * 8 + (cbase ^ (r & 7));
                bF[ni] = *reinterpret_cast<const bf16x8*>(Bs + (size_t)slot * 8);
            }
            #pragma unroll
            for (int mi = 0; mi < 4; ++mi)
                #pragma unroll
                for (int ni = 0; ni < 4; ++ni)
                    acc[mi][ni] = __builtin_amdgcn_mfma_f32_16x16x32_bf16(
                        aF[mi], bF[ni], acc[mi][ni], 0, 0, 0);
        }
        __syncthreads();
    }

    // plain stores of split-K partials (no atomics)
    // C/D layout (m89-verified): col = lane&15, row = (lane>>4)*4 + r
    float* Cz = Cp + (size_t)blockIdx.z * M * N;
    const int orow = blockIdx.x * TM + wm + (lane >> 4) * 4;
    const int ocol = blockIdx.y * TN + wn + (lane & 15);
    #pragma unroll
    for (int mi = 0; mi < 4; ++mi)
        #pragma unroll
        for (int ni = 0; ni < 4; ++ni)
            #pragma unroll
            for (int r = 0; r < 4; ++r)
                Cz[(size_t)(orow + mi * 16 + r) * N + ocol + ni * 16] =
                    acc[mi][ni][r];
}

// out = sum over SPLITK partials, float4-vectorized
__global__ __launch_bounds__(256) void reduce_k(
    const float* __restrict__ part, float* __restrict__ out, int n4)
{
    int idx = blockIdx.x * 256 + threadIdx.x;
    if (idx >= n4) return;
    const float4* p = reinterpret_cast<const float4*>(part);
    float4 a = p[idx];
    #pragma unroll
    for (int z = 1; z < SPLITK; ++z) {
        float4 b = p[(size_t)z * n4 + idx];
        a.x += b.x; a.y += b.y; a.z += b.z; a.w += b.w;
    }
    reinterpret_cast<float4*>(out)[idx] = a;
}

extern "C" void kernel_launch(void* const* d_in, const int* in_sizes, int n_in,
                              void* d_out, int out_size, void* d_ws, size_t ws_size,
                              hipStream_t stream)
{
    const float* x    = (const float*)d_in[0];   // [4096][512]
    const float* coef = (const float*)d_in[1];   // [512][512][8]
    float* out = (float*)d_out;                  // [4096][512]

    // workspace: partials fp32 [SPLITK][4096][512] (32 MB) + coef bf16 (4 MB)
    float* part = (float*)d_ws;
    unsigned short* coefb =
        (unsigned short*)(part + (size_t)SPLITK * BATCH * OSZ);

    int n4c = (OSZ * KDIM) / 4;                  // 524,288
    convert_bf16<<<(n4c + 255) / 256, 256, 0, stream>>>(coef, coefb, n4c);

    dim3 grid(BATCH / TM, OSZ / TN, SPLITK);     // 32 x 4 x 4 = 512 blocks
    gemm_fused<<<grid, 256, 0, stream>>>(x, coefb, part, BATCH, OSZ, KDIM);

    int n4r = (BATCH * OSZ) / 4;                 // 524,288
    reduce_k<<<(n4r + 255) / 256, 256, 0, stream>>>(part, out, n4r);
}